// Round 1
// baseline (104.844 us; speedup 1.0000x reference)
//
#include <hip/hip_runtime.h>
#include <stdint.h>

// FibonacciKAN: y[b,o] = sum_i sum_d F_d(tanh(x[b,i])) * C[i,o,d]
// F0..F5 = {0, 1, t, t^2+1, t^3+2t, t^4+3t^2+1}
// => y = bias[o] + sum_i ( t*W0 + t^2*W1 + t^3*W2 + t^4*W3 )[i,o]
// GEMM: M=32768, N=256, K=1024 (K = i-major x 4 powers).
//
// R7: restructure for phase overlap + bigger B reuse.
//  - 32x32x16 MFMA (2495 TF ceiling vs 2075 for 16x16x32, measured).
//  - Wave tile 128x32 (mt=4, nt=1): B-frag reused across 128 rows ->
//    L1 B pressure ~32 B/cyc/CU (was 53, limit ~60); B L2 traffic halves.
//  - Block 128x256, 8 waves (512 thr), grid 256 = 1 block/CU, 2 waves/SIMD.
//  - Chunked x staging pipelined into K loop (K is i-major: K-steps
//    [16c,16c+16) need only x cols [64c,64c+64)). T14 split: issue next
//    chunk's global loads BEFORE 12 K-steps, tanh+LDS-write after, one
//    barrier per chunk. Hides the 5.3us x-read burst under MFMA.
//  - bias folded into acc init (32x32 C layout: col = lane&31 for all regs).

typedef short bf16x8 __attribute__((ext_vector_type(8)));
typedef float f32x16 __attribute__((ext_vector_type(16)));
typedef unsigned int uint4v __attribute__((ext_vector_type(4)));

__device__ __forceinline__ unsigned int pack_bf16_trunc(float a, float b) {
  return __builtin_amdgcn_perm(__float_as_uint(b), __float_as_uint(a), 0x07060302u);
}
__device__ __forceinline__ unsigned int round_bf16_bits(float a) {
  unsigned int u = __float_as_uint(a);
  return u + 0x7fffu + ((u >> 16) & 1u);
}
__device__ __forceinline__ unsigned int pack_bf16_rne(float a, float b) {
  return __builtin_amdgcn_perm(round_bf16_bits(b), round_bf16_bits(a), 0x07060302u);
}
__device__ __forceinline__ float fast_tanh(float x) {
  float e = exp2f(x * 2.8853900817779268f);  // 2*log2(e)
  return 1.0f - 2.0f * __builtin_amdgcn_rcpf(e + 1.0f);
}

// ---------------- prep ----------------
// Bp frag layout for 32x32x16 B-operand: record = bf16x8 per lane,
// frag_idx = (ks*8 + (n>>5))*64 + lane, lane = ((i>>1)&1)*32 | (n&31),
// element j = (i&1)*4 + p, coeffs [w0, w1, c4, c5] for powers t^1..t^4.
__global__ void prep_kernel(const float* __restrict__ C, short* __restrict__ Bp,
                            float* __restrict__ bias) {
  int b = blockIdx.x;
  if (b < 256) {
    int i = b;
    int n = threadIdx.x;
    const float* c = C + (i * 256 + n) * 6;
    float c2 = c[2], c3 = c[3], c4_ = c[4], c5 = c[5];
    float w0 = c2 + 2.0f * c4_;
    float w1 = c3 + 3.0f * c5;
    unsigned int r0 = pack_bf16_rne(w0, w1);
    unsigned int r1 = pack_bf16_rne(c4_, c5);
    int ks = i >> 2;
    int lane = (((i >> 1) & 1) << 5) | (n & 31);
    int off = (((ks * 8 + (n >> 5)) * 64 + lane) << 3) + ((i & 1) << 2);
    *(uint2*)(Bp + off) = make_uint2(r0, r1);
  } else {
    int w = threadIdx.x >> 6;
    int t = threadIdx.x & 63;
    int n = (b - 256) * 4 + w;
    float s = 0.0f;
#pragma unroll
    for (int r = 0; r < 4; ++r) {
      int i = t + r * 64;
      const float* c = C + (i * 256 + n) * 6;
      s += c[1] + c[3] + c[5];
    }
#pragma unroll
    for (int off = 32; off > 0; off >>= 1) s += __shfl_down(s, off);
    if (t == 0) bias[n] = s;
  }
}

// ---------------- fused tanh + powers + GEMM ----------------
__global__ __launch_bounds__(512, 2) void fibkan_gemm(
    const float* __restrict__ x, const short* __restrict__ Bp,
    const float* __restrict__ bias, float* __restrict__ y) {
  __shared__ unsigned short tl[128 * 260];  // 66,560 B; stride 260 -> 2-way banks
  const int tid = threadIdx.x;
  const int lane = tid & 63;
  const int wv = tid >> 6;       // n-slice: cols [wv*32, wv*32+32)
  const int mb = blockIdx.x;     // rows [mb*128, mb*128+128)
  const int l5 = lane & 31, lhi = lane >> 5;

  const float4* xp = (const float4*)(x) + mb * 128 * 64;  // 64 float4 per row

  // acc init = bias broadcast (32x32 C/D: col = lane&31 for every reg)
  const float bv = bias[wv * 32 + l5];
  f32x16 acc[4];
#pragma unroll
  for (int mt = 0; mt < 4; ++mt)
#pragma unroll
    for (int r = 0; r < 16; ++r) acc[mt][r] = bv;

  // A-frag t source: lane needs t[row = mt*32+l5][i0,i1], i0 = ks*4 + lhi*2
  const unsigned short* tp0 = &tl[l5 * 260 + lhi * 2];
  // B-frag: bp[ks*512]
  const bf16x8* bp = (const bf16x8*)Bp + wv * 64 + lane;

  unsigned int tA[2][4];
  bf16x8 bB[2];

  // chunk c covers x float4-cols [c*16, c*16+16)  (i in [c*64, c*64+64))
  auto stage_load = [&](int c, float4* sv) {
#pragma unroll
    for (int it = 0; it < 4; ++it) {
      int j = tid + it * 512;  // 0..2047 = 128 rows x 16 cols
      int row = j >> 4, c4 = j & 15;
      sv[it] = xp[row * 64 + c * 16 + c4];
    }
  };
  auto stage_store = [&](int c, const float4* sv) {
#pragma unroll
    for (int it = 0; it < 4; ++it) {
      int j = tid + it * 512;
      int row = j >> 4, c4 = j & 15;
      uint2 pk = make_uint2(pack_bf16_rne(fast_tanh(sv[it].x), fast_tanh(sv[it].y)),
                            pack_bf16_rne(fast_tanh(sv[it].z), fast_tanh(sv[it].w)));
      *(uint2*)&tl[row * 260 + (c * 16 + c4) * 4] = pk;
    }
  };

  auto kstep = [&](int ks, int p, bool pfA) {
    bf16x8 af[4];
#pragma unroll
    for (int mt = 0; mt < 4; ++mt) {
      unsigned int tp2 = tA[p][mt];
      float ta = __uint_as_float(tp2 << 16);
      float tb = __uint_as_float(tp2 & 0xffff0000u);
      float ta2 = ta * ta, tb2 = tb * tb;
      float ta3 = ta2 * ta, tb3 = tb2 * tb;
      float ta4 = ta2 * ta2, tb4 = tb2 * tb2;
      uint4v u = {pack_bf16_trunc(ta, ta2), pack_bf16_trunc(ta3, ta4),
                  pack_bf16_trunc(tb, tb2), pack_bf16_trunc(tb3, tb4)};
      af[mt] = __builtin_bit_cast(bf16x8, u);
    }
#pragma unroll
    for (int mt = 0; mt < 4; ++mt)
      acc[mt] = __builtin_amdgcn_mfma_f32_32x32x16_bf16(af[mt], bB[p], acc[mt], 0, 0, 0);
    // B prefetch crosses chunk barriers freely (global, not LDS-dependent)
    int ksp = (ks + 2 <= 63) ? ks + 2 : 63;  // tail clamp: redundant, harmless
    bB[p] = bp[ksp * 512];
    if (pfA) {  // tA prefetch only within the staged chunk
#pragma unroll
      for (int mt = 0; mt < 4; ++mt)
        tA[p][mt] = *(const unsigned int*)(tp0 + mt * 32 * 260 + (ks + 2) * 4);
    }
  };

  // ---- prologue: chunk 0 serial, preload bB/tA for ks=0,1 ----
  {
    float4 sv[4];
    stage_load(0, sv);
    bB[0] = bp[0];
    bB[1] = bp[512];
    stage_store(0, sv);
    __syncthreads();
#pragma unroll
    for (int mt = 0; mt < 4; ++mt) {
      tA[0][mt] = *(const unsigned int*)(tp0 + mt * 32 * 260 + 0);
      tA[1][mt] = *(const unsigned int*)(tp0 + mt * 32 * 260 + 4);
    }
  }

  // ---- main: 4 chunks x 16 K-steps, next chunk staged under compute ----
  for (int c = 0; c < 4; ++c) {
    const int base = c * 16;
    float4 sv[4];
    if (c < 3) stage_load(c + 1, sv);        // issue early (T14)
#pragma unroll
    for (int s = 0; s < 12; ++s) kstep(base + s, s & 1, true);
    if (c < 3) stage_store(c + 1, sv);       // write late (waits only on sv)
    kstep(base + 12, 0, true);
    kstep(base + 13, 1, true);
    kstep(base + 14, 0, false);
    kstep(base + 15, 1, false);
    __syncthreads();
    if (c < 3) {
#pragma unroll
      for (int mt = 0; mt < 4; ++mt) {
        tA[0][mt] = *(const unsigned int*)(tp0 + mt * 32 * 260 + (base + 16) * 4);
        tA[1][mt] = *(const unsigned int*)(tp0 + mt * 32 * 260 + (base + 17) * 4);
      }
    }
  }

  // ---- epilogue: 32x32 C layout: col = l5, row = (r&3) + 8*(r>>2) + 4*lhi ----
  const int col = wv * 32 + l5;
  const int row0 = mb * 128 + lhi * 4;
#pragma unroll
  for (int mt = 0; mt < 4; ++mt) {
#pragma unroll
    for (int r = 0; r < 16; ++r) {
      int row = row0 + mt * 32 + (r & 3) + 8 * (r >> 2);
      y[row * 256 + col] = acc[mt][r];
    }
  }
}

extern "C" void kernel_launch(void* const* d_in, const int* in_sizes, int n_in,
                              void* d_out, int out_size, void* d_ws, size_t ws_size,
                              hipStream_t stream) {
  const float* x = (const float*)d_in[0];        // [32768, 256] f32
  const float* C = (const float*)d_in[1];        // [256, 256, 6] f32
  float* y = (float*)d_out;                      // [32768, 256] f32
  float* bias = (float*)d_ws;                    // 256 f32
  short* Bp = (short*)((char*)d_ws + 1024);      // 1024x256 bf16, frag-ordered
  prep_kernel<<<320, 256, 0, stream>>>(C, Bp, bias);
  fibkan_gemm<<<256, 512, 0, stream>>>(x, Bp, bias, y);
}

// Round 2
// 104.002 us; speedup vs baseline: 1.0081x; 1.0081x over previous
//
#include <hip/hip_runtime.h>
#include <stdint.h>

// FibonacciKAN: y[b,o] = sum_i sum_d F_d(tanh(x[b,i])) * C[i,o,d]
// F0..F5 = {0, 1, t, t^2+1, t^3+2t, t^4+3t^2+1}
// => y = bias[o] + sum_i ( t*W0 + t^2*W1 + t^3*W2 + t^4*W3 )[i,o]
// GEMM: M=32768, N=256, K=1024 (K = i-major x 4 powers).
//
// R8: occupancy probe / fix. R7 (128-row blocks, 1 block/CU, 2 waves/SIMD)
// was flat vs R6 => either (a) timed region is dominated by harness fill
// (42us @ 79% HBM peak) + ~45 reset() dispatches, or (b) gemm is
// latency-bound at low occupancy. R8 doubles hiding capacity:
//  - BM=64 blocks, grid 512, 512 thr (8 waves, wave tile 64x32, mt=2).
//  - 2 blocks/CU (LDS 33.3KB), 4 waves/SIMD (__launch_bounds__ cap 128 VGPR).
//  - Same 32x32x16 MFMA, same B layout, same chunked T14 staging, same
//    per-output accumulation order -> absmax unchanged (9.766e-4).
// Pre-commit: if dur_us stays ~102-105, overhead model confirmed -> ROOFLINE.

typedef short bf16x8 __attribute__((ext_vector_type(8)));
typedef float f32x16 __attribute__((ext_vector_type(16)));
typedef unsigned int uint4v __attribute__((ext_vector_type(4)));

__device__ __forceinline__ unsigned int pack_bf16_trunc(float a, float b) {
  return __builtin_amdgcn_perm(__float_as_uint(b), __float_as_uint(a), 0x07060302u);
}
__device__ __forceinline__ unsigned int round_bf16_bits(float a) {
  unsigned int u = __float_as_uint(a);
  return u + 0x7fffu + ((u >> 16) & 1u);
}
__device__ __forceinline__ unsigned int pack_bf16_rne(float a, float b) {
  return __builtin_amdgcn_perm(round_bf16_bits(b), round_bf16_bits(a), 0x07060302u);
}
__device__ __forceinline__ float fast_tanh(float x) {
  float e = exp2f(x * 2.8853900817779268f);  // 2*log2(e)
  return 1.0f - 2.0f * __builtin_amdgcn_rcpf(e + 1.0f);
}

// ---------------- prep (unchanged from R7) ----------------
// Bp frag layout for 32x32x16 B-operand: record = bf16x8 per lane,
// frag_idx = (ks*8 + (n>>5))*64 + lane, lane = ((i>>1)&1)*32 | (n&31),
// element j = (i&1)*4 + p, coeffs [w0, w1, c4, c5] for powers t^1..t^4.
__global__ void prep_kernel(const float* __restrict__ C, short* __restrict__ Bp,
                            float* __restrict__ bias) {
  int b = blockIdx.x;
  if (b < 256) {
    int i = b;
    int n = threadIdx.x;
    const float* c = C + (i * 256 + n) * 6;
    float c2 = c[2], c3 = c[3], c4_ = c[4], c5 = c[5];
    float w0 = c2 + 2.0f * c4_;
    float w1 = c3 + 3.0f * c5;
    unsigned int r0 = pack_bf16_rne(w0, w1);
    unsigned int r1 = pack_bf16_rne(c4_, c5);
    int ks = i >> 2;
    int lane = (((i >> 1) & 1) << 5) | (n & 31);
    int off = (((ks * 8 + (n >> 5)) * 64 + lane) << 3) + ((i & 1) << 2);
    *(uint2*)(Bp + off) = make_uint2(r0, r1);
  } else {
    int w = threadIdx.x >> 6;
    int t = threadIdx.x & 63;
    int n = (b - 256) * 4 + w;
    float s = 0.0f;
#pragma unroll
    for (int r = 0; r < 4; ++r) {
      int i = t + r * 64;
      const float* c = C + (i * 256 + n) * 6;
      s += c[1] + c[3] + c[5];
    }
#pragma unroll
    for (int off = 32; off > 0; off >>= 1) s += __shfl_down(s, off);
    if (t == 0) bias[n] = s;
  }
}

// ---------------- fused tanh + powers + GEMM ----------------
__global__ __launch_bounds__(512, 4) void fibkan_gemm(
    const float* __restrict__ x, const short* __restrict__ Bp,
    const float* __restrict__ bias, float* __restrict__ y) {
  __shared__ unsigned short tl[64 * 260];  // 33,280 B -> 2 blocks/CU
  const int tid = threadIdx.x;
  const int lane = tid & 63;
  const int wv = tid >> 6;       // n-slice: cols [wv*32, wv*32+32)
  const int mb = blockIdx.x;     // rows [mb*64, mb*64+64)
  const int l5 = lane & 31, lhi = lane >> 5;

  const float4* xp = (const float4*)(x) + mb * 64 * 64;  // 64 float4 per row

  // acc init = bias broadcast (32x32 C/D: col = lane&31 for every reg)
  const float bv = bias[wv * 32 + l5];
  f32x16 acc[2];
#pragma unroll
  for (int mt = 0; mt < 2; ++mt)
#pragma unroll
    for (int r = 0; r < 16; ++r) acc[mt][r] = bv;

  // A-frag t source: lane needs t[row = mt*32+l5][i0,i1], i0 = ks*4 + lhi*2
  const unsigned short* tp0 = &tl[l5 * 260 + lhi * 2];
  // B-frag: bp[ks*512]
  const bf16x8* bp = (const bf16x8*)Bp + wv * 64 + lane;

  unsigned int tA[2][2];
  bf16x8 bB[2];

  // chunk c covers x float4-cols [c*16, c*16+16)  (i in [c*64, c*64+64))
  auto stage_load = [&](int c, float4* sv) {
#pragma unroll
    for (int it = 0; it < 2; ++it) {
      int j = tid + it * 512;  // 0..1023 = 64 rows x 16 cols
      int row = j >> 4, c4 = j & 15;
      sv[it] = xp[row * 64 + c * 16 + c4];
    }
  };
  auto stage_store = [&](int c, const float4* sv) {
#pragma unroll
    for (int it = 0; it < 2; ++it) {
      int j = tid + it * 512;
      int row = j >> 4, c4 = j & 15;
      uint2 pk = make_uint2(pack_bf16_rne(fast_tanh(sv[it].x), fast_tanh(sv[it].y)),
                            pack_bf16_rne(fast_tanh(sv[it].z), fast_tanh(sv[it].w)));
      *(uint2*)&tl[row * 260 + (c * 16 + c4) * 4] = pk;
    }
  };

  auto kstep = [&](int ks, int p, bool pfA) {
    bf16x8 af[2];
#pragma unroll
    for (int mt = 0; mt < 2; ++mt) {
      unsigned int tp2 = tA[p][mt];
      float ta = __uint_as_float(tp2 << 16);
      float tb = __uint_as_float(tp2 & 0xffff0000u);
      float ta2 = ta * ta, tb2 = tb * tb;
      float ta3 = ta2 * ta, tb3 = tb2 * tb;
      float ta4 = ta2 * ta2, tb4 = tb2 * tb2;
      uint4v u = {pack_bf16_trunc(ta, ta2), pack_bf16_trunc(ta3, ta4),
                  pack_bf16_trunc(tb, tb2), pack_bf16_trunc(tb3, tb4)};
      af[mt] = __builtin_bit_cast(bf16x8, u);
    }
#pragma unroll
    for (int mt = 0; mt < 2; ++mt)
      acc[mt] = __builtin_amdgcn_mfma_f32_32x32x16_bf16(af[mt], bB[p], acc[mt], 0, 0, 0);
    // B prefetch crosses chunk barriers freely (global, not LDS-dependent)
    int ksp = (ks + 2 <= 63) ? ks + 2 : 63;  // tail clamp: redundant, harmless
    bB[p] = bp[ksp * 512];
    if (pfA) {  // tA prefetch only within the staged chunk
#pragma unroll
      for (int mt = 0; mt < 2; ++mt)
        tA[p][mt] = *(const unsigned int*)(tp0 + mt * 32 * 260 + (ks + 2) * 4);
    }
  };

  // ---- prologue: chunk 0 serial, preload bB/tA for ks=0,1 ----
  {
    float4 sv[2];
    stage_load(0, sv);
    bB[0] = bp[0];
    bB[1] = bp[512];
    stage_store(0, sv);
    __syncthreads();
#pragma unroll
    for (int mt = 0; mt < 2; ++mt) {
      tA[0][mt] = *(const unsigned int*)(tp0 + mt * 32 * 260 + 0);
      tA[1][mt] = *(const unsigned int*)(tp0 + mt * 32 * 260 + 4);
    }
  }

  // ---- main: 4 chunks x 16 K-steps, next chunk staged under compute ----
  for (int c = 0; c < 4; ++c) {
    const int base = c * 16;
    float4 sv[2];
    if (c < 3) stage_load(c + 1, sv);        // issue early (T14)
#pragma unroll
    for (int s = 0; s < 12; ++s) kstep(base + s, s & 1, true);
    if (c < 3) stage_store(c + 1, sv);       // write late (waits only on sv)
    kstep(base + 12, 0, true);
    kstep(base + 13, 1, true);
    kstep(base + 14, 0, false);
    kstep(base + 15, 1, false);
    __syncthreads();
    if (c < 3) {
#pragma unroll
      for (int mt = 0; mt < 2; ++mt) {
        tA[0][mt] = *(const unsigned int*)(tp0 + mt * 32 * 260 + (base + 16) * 4);
        tA[1][mt] = *(const unsigned int*)(tp0 + mt * 32 * 260 + (base + 17) * 4);
      }
    }
  }

  // ---- epilogue: 32x32 C layout: col = l5, row = (r&3) + 8*(r>>2) + 4*lhi ----
  const int col = wv * 32 + l5;
  const int row0 = mb * 64 + lhi * 4;
#pragma unroll
  for (int mt = 0; mt < 2; ++mt) {
#pragma unroll
    for (int r = 0; r < 16; ++r) {
      int row = row0 + mt * 32 + (r & 3) + 8 * (r >> 2);
      y[row * 256 + col] = acc[mt][r];
    }
  }
}

extern "C" void kernel_launch(void* const* d_in, const int* in_sizes, int n_in,
                              void* d_out, int out_size, void* d_ws, size_t ws_size,
                              hipStream_t stream) {
  const float* x = (const float*)d_in[0];        // [32768, 256] f32
  const float* C = (const float*)d_in[1];        // [256, 256, 6] f32
  float* y = (float*)d_out;                      // [32768, 256] f32
  float* bias = (float*)d_ws;                    // 256 f32
  short* Bp = (short*)((char*)d_ws + 1024);      // 1024x256 bf16, frag-ordered
  prep_kernel<<<320, 256, 0, stream>>>(C, Bp, bias);
  fibkan_gemm<<<512, 512, 0, stream>>>(x, Bp, bias, y);
}